// Round 4
// baseline (144.524 us; speedup 1.0000x reference)
//
#include <hip/hip_runtime.h>
#include <stdint.h>

#define Bn 16
#define Gn 128
#define Pn 8000
#define Rn 200
#define POSCAP 66
#define CANDN 1024
#define COLBLKS 512   // 16 batches * 32 blocks of 256 proposals
#define ROWBLKS 512   // 2048 (b,g) rows, 4 waves/block

typedef unsigned long long u64;

// Exact JAX threefry2x32 block (jax/_src/prng.py rotation schedule).
__device__ __forceinline__ void tf2x32(uint32_t k0, uint32_t k1,
                                       uint32_t x0, uint32_t x1,
                                       uint32_t& y0, uint32_t& y1) {
  uint32_t ks0 = k0, ks1 = k1, ks2 = k0 ^ k1 ^ 0x1BD11BDAu;
  x0 += ks0; x1 += ks1;
#define TF_ROUND(r) { x0 += x1; x1 = (x1 << (r)) | (x1 >> (32 - (r))); x1 ^= x0; }
  TF_ROUND(13) TF_ROUND(15) TF_ROUND(26) TF_ROUND(6)
  x0 += ks1; x1 += ks2 + 1u;
  TF_ROUND(17) TF_ROUND(29) TF_ROUND(16) TF_ROUND(24)
  x0 += ks2; x1 += ks0 + 2u;
  TF_ROUND(13) TF_ROUND(15) TF_ROUND(26) TF_ROUND(6)
  x0 += ks0; x1 += ks1 + 3u;
  TF_ROUND(17) TF_ROUND(29) TF_ROUND(16) TF_ROUND(24)
  x0 += ks1; x1 += ks2 + 4u;
  TF_ROUND(13) TF_ROUND(15) TF_ROUND(26) TF_ROUND(6)
  x0 += ks2; x1 += ks0 + 5u;
#undef TF_ROUND
  y0 = x0; y1 = x1;
}

// IoU, bit-exact vs reference float32 (no FMA contraction).
__device__ __forceinline__ float iou_f(float g0, float g1, float g2, float g3, float ag,
                                       float p0, float p1, float p2, float p3) {
  float iw = fmaxf(0.0f, __fsub_rn(fminf(g3, p3), fmaxf(g1, p1)));
  float ih = fmaxf(0.0f, __fsub_rn(fminf(g2, p2), fmaxf(g0, p0)));
  float inter = __fmul_rn(iw, ih);
  float ap = __fmul_rn(__fsub_rn(p3, p1), __fsub_rn(p2, p0));
  return __fdiv_rn(inter, __fsub_rn(__fadd_rn(ag, ap), inter));
}

// Phase 1, two block roles:
//  bt <  COLBLKS: thread per proposal -> col max/argmax over g (tie lowest g);
//                 emits u16 combo = (prelim_cls<<8)|parg. gt loads are uniform
//                 (blockIdx/loop-var indexed) -> scalar loads.
//  bt >= COLBLKS: wave per (b,g) row -> row argmax over p (tie lowest p);
//                 direct store of packed (fbits(iou)<<32 | ~p), 0 if gt invalid.
__global__ __launch_bounds__(256) void k_phase1(const float* __restrict__ gt,
                                                const float* __restrict__ pr,
                                                uint16_t* __restrict__ combo,
                                                u64* __restrict__ rowpk) {
  int bt = blockIdx.x, tid = threadIdx.x;
  if (bt < COLBLKS) {
    int b = bt >> 5;
    int p = ((bt & 31) << 8) + tid;
    if (p >= Pn) return;
    const float* pb = pr + ((size_t)b * Pn + p) * 5;
    float p0 = pb[0], p1 = pb[1], p2 = pb[2], p3 = pb[3], pv = pb[4];
    int prelim = 0, bidx = 0;
    if (pv != 0.0f) {
      const float* gbase = gt + (size_t)b * Gn * 5;
      float best = -2.0f;
      for (int g = 0; g < Gn; g++) {
        float gv = gbase[g * 5 + 4];
        if (gv != 0.0f) {
          float g0 = gbase[g * 5 + 0], g1 = gbase[g * 5 + 1];
          float g2 = gbase[g * 5 + 2], g3 = gbase[g * 5 + 3];
          float ag = __fmul_rn(__fsub_rn(g3, g1), __fsub_rn(g2, g0));
          float v = iou_f(g0, g1, g2, g3, ag, p0, p1, p2, p3);
          if (v > best) { best = v; bidx = g; }  // ascending g => lowest g on tie
        }
      }
      prelim = (best >= 0.5f) ? 2 : 1;
    }
    combo[(size_t)b * Pn + p] = (uint16_t)((prelim << 8) | bidx);
  } else {
    int row = (bt - COLBLKS) * 4 + (tid >> 6);  // b*128+g
    int lane = tid & 63;
    int b = row >> 7;
    const float* gb = gt + (size_t)row * 5;
    float gv = gb[4];
    u64 key = 0;
    if (gv != 0.0f) {
      float g0 = gb[0], g1 = gb[1], g2 = gb[2], g3 = gb[3];
      float ag = __fmul_rn(__fsub_rn(g3, g1), __fsub_rn(g2, g0));
      const float* prb = pr + (size_t)b * Pn * 5;
      float best = -2.0f; int bidx = 0;
      for (int p = lane; p < Pn; p += 64) {
        const float* pb = prb + (size_t)p * 5;
        float pv = pb[4];
        if (pv != 0.0f) {
          float v = iou_f(g0, g1, g2, g3, ag, pb[0], pb[1], pb[2], pb[3]);
          if (v > best) { best = v; bidx = p; }  // ascending p => lowest p on tie
        }
      }
      for (int off = 32; off > 0; off >>= 1) {
        float ov = __shfl_down(best, off);
        int oi = __shfl_down(bidx, off);
        if (ov > best || (ov == best && oi < bidx)) { best = ov; bidx = oi; }
      }
      key = ((u64)__float_as_uint(best) << 32) | (unsigned)(~bidx);
    }
    if (lane == 0) rowpk[row] = key;
  }
}

// Per-batch: removed bitmap from row winners, PRNG+classify+histogram,
// threshold scan, candidate gather, 1024-wide bitonic sort, epilogue.
__global__ __launch_bounds__(1024) void k_select(
    const float* __restrict__ gt, const int* __restrict__ gtc,
    const float* __restrict__ pr, const uint16_t* __restrict__ combo,
    const u64* __restrict__ rowpk, float* __restrict__ out) {
  __shared__ uint32_t skey[Pn];           // 32 KB: (cls<<23)|val23
  __shared__ uint32_t hist2[1024];
  __shared__ uint32_t hist1[1024];
  __shared__ u64 cand[CANDN];             // 8 KB
  __shared__ uint32_t rembm[Pn / 32 + 1];
  __shared__ int matched[Gn];
  __shared__ int s_npos, s_nneg, s_miss, s_call, s_cpos, s_T2, s_T1;
  __shared__ uint32_t s_keys[4];
  int b = blockIdx.x, tid = threadIdx.x;

  hist2[tid] = 0; hist1[tid] = 0; cand[tid] = 0ull;
  if (tid < Pn / 32 + 1) rembm[tid] = 0;
  if (tid < Gn) matched[tid] = 0;
  if (tid == 0) {
    s_npos = 0; s_nneg = 0; s_miss = 0; s_call = 0; s_cpos = 0;
    s_T2 = 1025; s_T1 = 1025;
    // partitionable threefry: keys=split((0,42),16)[b]=tf(...,0,b); k1,k2=split
    uint32_t kb0, kb1, a0, a1, c0, c1;
    tf2x32(0u, 42u, 0u, (uint32_t)b, kb0, kb1);
    tf2x32(kb0, kb1, 0u, 0u, a0, a1);
    tf2x32(kb0, kb1, 0u, 1u, c0, c1);
    s_keys[0] = a0; s_keys[1] = a1; s_keys[2] = c0; s_keys[3] = c1;
  }
  __syncthreads();

  if (tid < Gn) {
    u64 pk = rowpk[(size_t)b * Gn + tid];
    if (pk != 0ull) {
      unsigned p = ~(unsigned)(pk & 0xFFFFFFFFull);
      atomicOr(&rembm[p >> 5], 1u << (p & 31));
    }
  }
  __syncthreads();

  uint32_t k10 = s_keys[0], k11 = s_keys[1], k20 = s_keys[2], k21 = s_keys[3];
  const size_t bp = (size_t)b * Pn;
  int lpos = 0, lneg = 0;
  for (int p = tid; p < Pn; p += 1024) {
    uint32_t cb = combo[bp + p];
    int rem = (rembm[p >> 5] >> (p & 31)) & 1;
    int cls = rem ? 0 : (int)(cb >> 8);
    uint32_t key = 0;
    if (cls) {
      uint32_t kk0 = (cls == 2) ? k10 : k20, kk1 = (cls == 2) ? k11 : k21;
      uint32_t y0, y1;
      tf2x32(kk0, kk1, 0u, (uint32_t)p, y0, y1);
      uint32_t val = (y0 ^ y1) >> 9;
      key = ((uint32_t)cls << 23) | val;
      if (cls == 2) { lpos++; matched[cb & 127] = 1; atomicAdd(&hist2[val >> 13], 1u); }
      else { lneg++; atomicAdd(&hist1[val >> 13], 1u); }
    }
    skey[p] = key;
  }
  if (lpos) atomicAdd(&s_npos, lpos);
  if (lneg) atomicAdd(&s_nneg, lneg);
  __syncthreads();

  // threshold scan: wave0 -> positives, wave1 -> negatives
  if (tid < 128) {
    bool isP = tid < 64;
    int lane = tid & 63;
    uint32_t* hist = isP ? hist2 : hist1;
    int cnt = isP ? s_npos : s_nneg;
    int cap = isP ? POSCAP : Rn;
    int need = cnt < cap ? cnt : cap;
    int base = 1024 - 16 * (lane + 1);
    int local = 0;
#pragma unroll
    for (int j = 0; j < 16; j++) local += (int)hist[base + j];
    int incl = local;
    for (int d = 1; d < 64; d <<= 1) {
      int o = __shfl_up(incl, d);
      if (lane >= d) incl += o;
    }
    int above = incl - local;  // strictly-above-range count
    if (need > 0 && above < need && above + local >= need) {
      int cum = above, T = base;
      for (int j = 15; j >= 0; j--) {
        cum += (int)hist[base + j];
        if (cum >= need) { T = base + j; break; }
      }
      if (isP) s_T2 = T; else s_T1 = T;
    }
  }
  __syncthreads();
  int T2 = s_T2, T1 = s_T1;

  for (int p = tid; p < Pn; p += 1024) {
    uint32_t key = skey[p];
    int cls = (int)(key >> 23);
    if (cls) {
      int bucket = (int)((key & 0x7FFFFFu) >> 13);
      int T = (cls == 2) ? T2 : T1;
      if (bucket >= T) {
        int slot = atomicAdd(&s_call, 1);
        if (slot < CANDN) {
          cand[slot] = ((u64)key << 16) | (uint32_t)((uint16_t)(~p));
          if (cls == 2) atomicAdd(&s_cpos, 1);
        }
      }
    }
  }
  __syncthreads();

  // bitonic sort desc on u64 (strict total order: cls, val desc, idx asc)
  for (unsigned k = 2; k <= CANDN; k <<= 1) {
    for (unsigned j = k >> 1; j > 0; j >>= 1) {
      unsigned i = tid, l = i ^ j;
      if (l > i) {
        u64 av = cand[i], cv = cand[l];
        bool a_first = av > cv;
        bool desc = ((i & k) == 0u);
        if (desc != a_first) { cand[i] = cv; cand[l] = av; }
      }
      __syncthreads();
    }
  }

  int npos = s_npos, nneg = s_nneg, cpos = s_cpos;
  int n_pos = npos < POSCAP ? npos : POSCAP;
  int rems = Rn - n_pos;
  int n_neg = nneg < rems ? nneg : rems;

  float* o_del = out;
  float* o_cls = out + (size_t)Bn * Rn * 5;
  float* o_roi = out + (size_t)Bn * Rn * 7;
  float* o_mis = out + (size_t)Bn * Rn * 12;

  if (tid < Rn) {
    int s = tid;
    bool is_pos = s < n_pos;
    bool is_real = s < n_pos + n_neg;
    float d0 = 0, d1 = 0, d2 = 0, d3 = 0, d4 = 0, c0 = 0, c1 = 0;
    float r0 = 0, r1 = 0, r2 = 0, r3 = 0, r4 = 0;
    if (is_real) {
      int ci = is_pos ? s : (cpos + (s - n_pos));
      u64 ck = cand[ci];
      int p = (int)((~(unsigned)ck) & 0xFFFFu);
      const float* pb = pr + (bp + p) * 5;
      float q0 = pb[0], q1 = pb[1], q2 = pb[2], q3 = pb[3];
      r0 = q0; r1 = q1; r2 = q2; r3 = q3; r4 = 1.0f; c1 = 1.0f;
      if (is_pos) {
        int g = (int)(combo[bp + p] & 127);
        const float* gb = gt + ((size_t)b * Gn + g) * 5;
        float g0 = gb[0], g1 = gb[1], g2 = gb[2], g3 = gb[3];
        float h = __fsub_rn(q2, q0), w = __fsub_rn(q3, q1);
        float gh = __fsub_rn(g2, g0), gw = __fsub_rn(g3, g1);
        float cy = __fmul_rn(__fadd_rn(q2, q0), 0.5f);
        float cx = __fmul_rn(__fadd_rn(q3, q1), 0.5f);
        float gcy = __fmul_rn(__fadd_rn(g2, g0), 0.5f);
        float gcx = __fmul_rn(__fadd_rn(g3, g1), 0.5f);
        float dy = __fdiv_rn(__fsub_rn(gcy, cy), h);
        float dx = __fdiv_rn(__fsub_rn(gcx, cx), w);
        float dh = logf(fmaxf(__fdiv_rn(gh, h), 1e-8f));
        float dw = logf(fmaxf(__fdiv_rn(gw, w), 1e-8f));
        d0 = __fdiv_rn(dy, 0.1f); d1 = __fdiv_rn(dx, 0.1f);
        d2 = __fdiv_rn(dh, 0.2f); d3 = __fdiv_rn(dw, 0.2f);
        d4 = 1.0f;
        c0 = (float)gtc[((size_t)b * Gn + g) * 2];
      } else {
        d4 = -1.0f;
      }
    }
    size_t ob = (size_t)b * Rn + s;
    o_del[ob * 5 + 0] = d0; o_del[ob * 5 + 1] = d1; o_del[ob * 5 + 2] = d2;
    o_del[ob * 5 + 3] = d3; o_del[ob * 5 + 4] = d4;
    o_cls[ob * 2 + 0] = c0; o_cls[ob * 2 + 1] = c1;
    o_roi[ob * 5 + 0] = r0; o_roi[ob * 5 + 1] = r1; o_roi[ob * 5 + 2] = r2;
    o_roi[ob * 5 + 3] = r3; o_roi[ob * 5 + 4] = r4;
  }

  if (tid < Gn) {
    float gv = gt[((size_t)b * Gn + tid) * 5 + 4];
    if (gv != 0.0f && matched[tid] == 0) atomicAdd(&s_miss, 1);
  }
  __syncthreads();
  if (tid == 0) o_mis[b] = (float)s_miss;
}

extern "C" void kernel_launch(void* const* d_in, const int* in_sizes, int n_in,
                              void* d_out, int out_size, void* d_ws, size_t ws_size,
                              hipStream_t stream) {
  const float* gt = (const float*)d_in[0];
  const int* gtc = (const int*)d_in[1];
  const float* pr = (const float*)d_in[2];
  float* out = (float*)d_out;

  u64* rowpk = (u64*)d_ws;                            // B*G u64 = 16 KB
  uint16_t* combo = (uint16_t*)(rowpk + Bn * Gn);     // B*P u16 = 256 KB

  k_phase1<<<COLBLKS + ROWBLKS, 256, 0, stream>>>(gt, pr, combo, rowpk);
  k_select<<<Bn, 1024, 0, stream>>>(gt, gtc, pr, combo, rowpk, out);
}

// Round 5
// 138.276 us; speedup vs baseline: 1.0452x; 1.0452x over previous
//
#include <hip/hip_runtime.h>
#include <stdint.h>

#define Bn 16
#define Gn 128
#define Pn 8000
#define Rn 200
#define POSCAP 66
#define CANDN 512
#define SLICES 32
#define TILE 250

typedef unsigned long long u64;

// Exact JAX threefry2x32 block (jax/_src/prng.py rotation schedule).
__device__ __forceinline__ void tf2x32(uint32_t k0, uint32_t k1,
                                       uint32_t x0, uint32_t x1,
                                       uint32_t& y0, uint32_t& y1) {
  uint32_t ks0 = k0, ks1 = k1, ks2 = k0 ^ k1 ^ 0x1BD11BDAu;
  x0 += ks0; x1 += ks1;
#define TF_ROUND(r) { x0 += x1; x1 = (x1 << (r)) | (x1 >> (32 - (r))); x1 ^= x0; }
  TF_ROUND(13) TF_ROUND(15) TF_ROUND(26) TF_ROUND(6)
  x0 += ks1; x1 += ks2 + 1u;
  TF_ROUND(17) TF_ROUND(29) TF_ROUND(16) TF_ROUND(24)
  x0 += ks2; x1 += ks0 + 2u;
  TF_ROUND(13) TF_ROUND(15) TF_ROUND(26) TF_ROUND(6)
  x0 += ks0; x1 += ks1 + 3u;
  TF_ROUND(17) TF_ROUND(29) TF_ROUND(16) TF_ROUND(24)
  x0 += ks1; x1 += ks2 + 4u;
  TF_ROUND(13) TF_ROUND(15) TF_ROUND(26) TF_ROUND(6)
  x0 += ks2; x1 += ks0 + 5u;
#undef TF_ROUND
  y0 = x0; y1 = x1;
}

// IoU, bit-exact vs reference float32 (no FMA contraction).
__device__ __forceinline__ float iou_f(float g0, float g1, float g2, float g3, float ag,
                                       float p0, float p1, float p2, float p3) {
  float iw = fmaxf(0.0f, __fsub_rn(fminf(g3, p3), fmaxf(g1, p1)));
  float ih = fmaxf(0.0f, __fsub_rn(fminf(g2, p2), fmaxf(g0, p0)));
  float inter = __fmul_rn(iw, ih);
  float ap = __fmul_rn(__fsub_rn(p3, p1), __fsub_rn(p2, p0));
  return __fdiv_rn(inter, __fsub_rn(__fadd_rn(ag, ap), inter));
}

// One block per (batch, slice of 250 proposals). Stage tile+gt in LDS once.
// Col role: thread t -> col max/argmax over g (tie lowest g), emit u16 combo.
// Row role: wave w owns 32 g's -> tile-local row max via u64 shfl reduce,
// direct store of packed (fbits(iou)<<32 | ~p) to rowpk2[b][slice][g] (0 if
// gt invalid / no valid proposal in tile). No atomics, no memset needed.
__global__ __launch_bounds__(256) void k_phase1(const float* __restrict__ gt,
                                                const float* __restrict__ pr,
                                                uint16_t* __restrict__ combo,
                                                u64* __restrict__ rowpk2) {
  __shared__ float sp[TILE * 5];   // 5 KB, AoS stride-5 (2-way bank alias: free)
  __shared__ float sg[Gn * 5];     // 2.5 KB
  int blk = blockIdx.x;
  int b = blk >> 5, s = blk & 31;
  int tid = threadIdx.x;
  const float* prb = pr + ((size_t)b * Pn + s * TILE) * 5;
  for (int i = tid; i < TILE * 5; i += 256) sp[i] = prb[i];
  for (int i = tid; i < Gn * 5; i += 256) sg[i] = gt[(size_t)b * Gn * 5 + i];
  __syncthreads();

  // ---- col role ----
  if (tid < TILE) {
    float p0 = sp[tid * 5], p1 = sp[tid * 5 + 1], p2 = sp[tid * 5 + 2];
    float p3 = sp[tid * 5 + 3], pv = sp[tid * 5 + 4];
    int prelim = 0, bidx = 0;
    if (pv != 0.0f) {
      float best = -2.0f;
      for (int g = 0; g < Gn; g++) {
        float gv = sg[g * 5 + 4];
        if (gv != 0.0f) {
          float g0 = sg[g * 5], g1 = sg[g * 5 + 1], g2 = sg[g * 5 + 2], g3 = sg[g * 5 + 3];
          float ag = __fmul_rn(__fsub_rn(g3, g1), __fsub_rn(g2, g0));
          float v = iou_f(g0, g1, g2, g3, ag, p0, p1, p2, p3);
          if (v > best) { best = v; bidx = g; }  // ascending g => lowest g on tie
        }
      }
      prelim = (best >= 0.5f) ? 2 : 1;
    }
    combo[(size_t)b * Pn + s * TILE + tid] = (uint16_t)((prelim << 8) | bidx);
  }

  // ---- row role ----
  int wave = tid >> 6, lane = tid & 63;
  for (int gi = 0; gi < 32; gi++) {
    int g = wave * 32 + gi;
    float gv = sg[g * 5 + 4];   // wave-uniform broadcast
    u64 key = 0;
    if (gv != 0.0f) {
      float g0 = sg[g * 5], g1 = sg[g * 5 + 1], g2 = sg[g * 5 + 2], g3 = sg[g * 5 + 3];
      float ag = __fmul_rn(__fsub_rn(g3, g1), __fsub_rn(g2, g0));
#pragma unroll
      for (int k = 0; k < 4; k++) {
        int p = lane + k * 64;
        if (p < TILE) {
          float pv = sp[p * 5 + 4];
          if (pv != 0.0f) {
            float v = iou_f(g0, g1, g2, g3, ag, sp[p * 5], sp[p * 5 + 1],
                            sp[p * 5 + 2], sp[p * 5 + 3]);
            u64 kk = ((u64)__float_as_uint(v) << 32) | (unsigned)(~(s * TILE + p));
            if (kk > key) key = kk;   // iou desc, then lowest p (~p asc)
          }
        }
      }
      for (int off = 32; off > 0; off >>= 1) {
        u64 o = __shfl_down(key, off);
        if (o > key) key = o;
      }
    }
    if (lane == 0) rowpk2[((size_t)b * SLICES + s) * Gn + g] = key;
  }
}

// Per-batch: reduce rowpk2 -> removed bitmap, PRNG+classify+histogram,
// threshold scan, candidate gather, 512-wide bitonic sort, epilogue.
__global__ __launch_bounds__(1024) void k_select(
    const float* __restrict__ gt, const int* __restrict__ gtc,
    const float* __restrict__ pr, const uint16_t* __restrict__ combo,
    const u64* __restrict__ rowpk2, float* __restrict__ out) {
  __shared__ uint32_t skey[Pn];           // 32 KB: (cls<<23)|val23
  __shared__ uint32_t hist2[1024];
  __shared__ uint32_t hist1[1024];
  __shared__ u64 cand[CANDN];             // 4 KB
  __shared__ uint32_t rembm[Pn / 32 + 1];
  __shared__ int matched[Gn];
  __shared__ int s_npos, s_nneg, s_miss, s_call, s_cpos, s_T2, s_T1;
  __shared__ uint32_t s_keys[4];
  int b = blockIdx.x, tid = threadIdx.x;

  hist2[tid] = 0; hist1[tid] = 0;
  if (tid < CANDN) cand[tid] = 0ull;
  if (tid < Pn / 32 + 1) rembm[tid] = 0;
  if (tid < Gn) matched[tid] = 0;
  if (tid == 0) {
    s_npos = 0; s_nneg = 0; s_miss = 0; s_call = 0; s_cpos = 0;
    s_T2 = 1025; s_T1 = 1025;
    // partitionable threefry: keys=split((0,42),16)[b]=tf(...,0,b); k1,k2=split
    uint32_t kb0, kb1, a0, a1, c0, c1;
    tf2x32(0u, 42u, 0u, (uint32_t)b, kb0, kb1);
    tf2x32(kb0, kb1, 0u, 0u, a0, a1);
    tf2x32(kb0, kb1, 0u, 1u, c0, c1);
    s_keys[0] = a0; s_keys[1] = a1; s_keys[2] = c0; s_keys[3] = c1;
  }
  __syncthreads();

  if (tid < Gn) {
    u64 m = 0;
    const u64* rp = rowpk2 + (size_t)b * SLICES * Gn + tid;
#pragma unroll 8
    for (int sl = 0; sl < SLICES; sl++) {
      u64 v = rp[sl * Gn];
      if (v > m) m = v;
    }
    if (m != 0ull) {
      unsigned p = ~(unsigned)(m & 0xFFFFFFFFull);
      atomicOr(&rembm[p >> 5], 1u << (p & 31));
    }
  }
  __syncthreads();

  uint32_t k10 = s_keys[0], k11 = s_keys[1], k20 = s_keys[2], k21 = s_keys[3];
  const size_t bp = (size_t)b * Pn;
  int lpos = 0, lneg = 0;
  for (int p = tid; p < Pn; p += 1024) {
    uint32_t cb = combo[bp + p];
    int rem = (rembm[p >> 5] >> (p & 31)) & 1;
    int cls = rem ? 0 : (int)(cb >> 8);
    uint32_t key = 0;
    if (cls) {
      uint32_t kk0 = (cls == 2) ? k10 : k20, kk1 = (cls == 2) ? k11 : k21;
      uint32_t y0, y1;
      tf2x32(kk0, kk1, 0u, (uint32_t)p, y0, y1);
      uint32_t val = (y0 ^ y1) >> 9;
      key = ((uint32_t)cls << 23) | val;
      if (cls == 2) { lpos++; matched[cb & 127] = 1; atomicAdd(&hist2[val >> 13], 1u); }
      else { lneg++; atomicAdd(&hist1[val >> 13], 1u); }
    }
    skey[p] = key;
  }
  if (lpos) atomicAdd(&s_npos, lpos);
  if (lneg) atomicAdd(&s_nneg, lneg);
  __syncthreads();

  // threshold scan: wave0 -> positives, wave1 -> negatives
  if (tid < 128) {
    bool isP = tid < 64;
    int lane = tid & 63;
    uint32_t* hist = isP ? hist2 : hist1;
    int cnt = isP ? s_npos : s_nneg;
    int cap = isP ? POSCAP : Rn;
    int need = cnt < cap ? cnt : cap;
    int base = 1024 - 16 * (lane + 1);
    int local = 0;
#pragma unroll
    for (int j = 0; j < 16; j++) local += (int)hist[base + j];
    int incl = local;
    for (int d = 1; d < 64; d <<= 1) {
      int o = __shfl_up(incl, d);
      if (lane >= d) incl += o;
    }
    int above = incl - local;  // strictly-above-range count
    if (need > 0 && above < need && above + local >= need) {
      int cum = above, T = base;
      for (int j = 15; j >= 0; j--) {
        cum += (int)hist[base + j];
        if (cum >= need) { T = base + j; break; }
      }
      if (isP) s_T2 = T; else s_T1 = T;
    }
  }
  __syncthreads();
  int T2 = s_T2, T1 = s_T1;

  for (int p = tid; p < Pn; p += 1024) {
    uint32_t key = skey[p];
    int cls = (int)(key >> 23);
    if (cls) {
      int bucket = (int)((key & 0x7FFFFFu) >> 13);
      int T = (cls == 2) ? T2 : T1;
      if (bucket >= T) {
        int slot = atomicAdd(&s_call, 1);
        if (slot < CANDN) {
          cand[slot] = ((u64)key << 16) | (uint32_t)((uint16_t)(~p));
          if (cls == 2) atomicAdd(&s_cpos, 1);
        }
      }
    }
  }
  __syncthreads();

  // bitonic sort desc on u64 (strict total order: cls, val desc, idx asc)
  for (unsigned k = 2; k <= CANDN; k <<= 1) {
    for (unsigned j = k >> 1; j > 0; j >>= 1) {
      unsigned i = tid, l = i ^ j;
      if (i < CANDN && l > i) {
        u64 av = cand[i], cv = cand[l];
        bool a_first = av > cv;
        bool desc = ((i & k) == 0u);
        if (desc != a_first) { cand[i] = cv; cand[l] = av; }
      }
      __syncthreads();
    }
  }

  int npos = s_npos, nneg = s_nneg, cpos = s_cpos;
  int n_pos = npos < POSCAP ? npos : POSCAP;
  int rems = Rn - n_pos;
  int n_neg = nneg < rems ? nneg : rems;

  float* o_del = out;
  float* o_cls = out + (size_t)Bn * Rn * 5;
  float* o_roi = out + (size_t)Bn * Rn * 7;
  float* o_mis = out + (size_t)Bn * Rn * 12;

  if (tid < Rn) {
    int s = tid;
    bool is_pos = s < n_pos;
    bool is_real = s < n_pos + n_neg;
    float d0 = 0, d1 = 0, d2 = 0, d3 = 0, d4 = 0, c0 = 0, c1 = 0;
    float r0 = 0, r1 = 0, r2 = 0, r3 = 0, r4 = 0;
    if (is_real) {
      int ci = is_pos ? s : (cpos + (s - n_pos));
      u64 ck = cand[ci];
      int p = (int)((~(unsigned)ck) & 0xFFFFu);
      const float* pb = pr + (bp + p) * 5;
      float q0 = pb[0], q1 = pb[1], q2 = pb[2], q3 = pb[3];
      r0 = q0; r1 = q1; r2 = q2; r3 = q3; r4 = 1.0f; c1 = 1.0f;
      if (is_pos) {
        int g = (int)(combo[bp + p] & 127);
        const float* gb = gt + ((size_t)b * Gn + g) * 5;
        float g0 = gb[0], g1 = gb[1], g2 = gb[2], g3 = gb[3];
        float h = __fsub_rn(q2, q0), w = __fsub_rn(q3, q1);
        float gh = __fsub_rn(g2, g0), gw = __fsub_rn(g3, g1);
        float cy = __fmul_rn(__fadd_rn(q2, q0), 0.5f);
        float cx = __fmul_rn(__fadd_rn(q3, q1), 0.5f);
        float gcy = __fmul_rn(__fadd_rn(g2, g0), 0.5f);
        float gcx = __fmul_rn(__fadd_rn(g3, g1), 0.5f);
        float dy = __fdiv_rn(__fsub_rn(gcy, cy), h);
        float dx = __fdiv_rn(__fsub_rn(gcx, cx), w);
        float dh = logf(fmaxf(__fdiv_rn(gh, h), 1e-8f));
        float dw = logf(fmaxf(__fdiv_rn(gw, w), 1e-8f));
        d0 = __fdiv_rn(dy, 0.1f); d1 = __fdiv_rn(dx, 0.1f);
        d2 = __fdiv_rn(dh, 0.2f); d3 = __fdiv_rn(dw, 0.2f);
        d4 = 1.0f;
        c0 = (float)gtc[((size_t)b * Gn + g) * 2];
      } else {
        d4 = -1.0f;
      }
    }
    size_t ob = (size_t)b * Rn + s;
    o_del[ob * 5 + 0] = d0; o_del[ob * 5 + 1] = d1; o_del[ob * 5 + 2] = d2;
    o_del[ob * 5 + 3] = d3; o_del[ob * 5 + 4] = d4;
    o_cls[ob * 2 + 0] = c0; o_cls[ob * 2 + 1] = c1;
    o_roi[ob * 5 + 0] = r0; o_roi[ob * 5 + 1] = r1; o_roi[ob * 5 + 2] = r2;
    o_roi[ob * 5 + 3] = r3; o_roi[ob * 5 + 4] = r4;
  }

  if (tid < Gn) {
    float gv = gt[((size_t)b * Gn + tid) * 5 + 4];
    if (gv != 0.0f && matched[tid] == 0) atomicAdd(&s_miss, 1);
  }
  __syncthreads();
  if (tid == 0) o_mis[b] = (float)s_miss;
}

extern "C" void kernel_launch(void* const* d_in, const int* in_sizes, int n_in,
                              void* d_out, int out_size, void* d_ws, size_t ws_size,
                              hipStream_t stream) {
  const float* gt = (const float*)d_in[0];
  const int* gtc = (const int*)d_in[1];
  const float* pr = (const float*)d_in[2];
  float* out = (float*)d_out;

  u64* rowpk2 = (u64*)d_ws;                              // B*SLICES*G u64 = 512 KB
  uint16_t* combo = (uint16_t*)(rowpk2 + Bn * SLICES * Gn);  // B*P u16 = 256 KB

  k_phase1<<<Bn * SLICES, 256, 0, stream>>>(gt, pr, combo, rowpk2);
  k_select<<<Bn, 1024, 0, stream>>>(gt, gtc, pr, combo, rowpk2, out);
}

// Round 6
// 113.651 us; speedup vs baseline: 1.2716x; 1.2167x over previous
//
#include <hip/hip_runtime.h>
#include <stdint.h>

#define Bn 16
#define Gn 128
#define Pn 8000
#define Rn 200
#define POSCAP 66
#define CANDN 512
#define SLICES 64
#define TILE 125

typedef unsigned long long u64;

// Exact JAX threefry2x32 block (jax/_src/prng.py rotation schedule).
__device__ __forceinline__ void tf2x32(uint32_t k0, uint32_t k1,
                                       uint32_t x0, uint32_t x1,
                                       uint32_t& y0, uint32_t& y1) {
  uint32_t ks0 = k0, ks1 = k1, ks2 = k0 ^ k1 ^ 0x1BD11BDAu;
  x0 += ks0; x1 += ks1;
#define TF_ROUND(r) { x0 += x1; x1 = (x1 << (r)) | (x1 >> (32 - (r))); x1 ^= x0; }
  TF_ROUND(13) TF_ROUND(15) TF_ROUND(26) TF_ROUND(6)
  x0 += ks1; x1 += ks2 + 1u;
  TF_ROUND(17) TF_ROUND(29) TF_ROUND(16) TF_ROUND(24)
  x0 += ks2; x1 += ks0 + 2u;
  TF_ROUND(13) TF_ROUND(15) TF_ROUND(26) TF_ROUND(6)
  x0 += ks0; x1 += ks1 + 3u;
  TF_ROUND(17) TF_ROUND(29) TF_ROUND(16) TF_ROUND(24)
  x0 += ks1; x1 += ks2 + 4u;
  TF_ROUND(13) TF_ROUND(15) TF_ROUND(26) TF_ROUND(6)
  x0 += ks2; x1 += ks0 + 5u;
#undef TF_ROUND
  y0 = x0; y1 = x1;
}

// IoU from padded boxes (area precomputed; NaN area => NaN iou => never wins).
// Bit-exact vs reference float32 (no FMA contraction; same op association).
__device__ __forceinline__ float iou_pk(const float4& g, float ga,
                                        const float4& p, float pa) {
  float iw = fmaxf(0.0f, __fsub_rn(fminf(g.w, p.w), fmaxf(g.y, p.y)));
  float ih = fmaxf(0.0f, __fsub_rn(fminf(g.z, p.z), fmaxf(g.x, p.x)));
  float inter = __fmul_rn(iw, ih);
  return __fdiv_rn(inter, __fsub_rn(__fadd_rn(ga, pa), inter));
}

// One block per (batch, 125-proposal slice). Boxes staged stride-8 in LDS
// (b128+b32 broadcast reads in the loops; validity folded into area=NaN).
// Waves 0-1: lane = one g row; sequential scan of tile -> register argmax
//            (tie lowest p), direct coalesced u64 store. No shuffles/atomics.
// Waves 2-3: lane = one proposal col; loop 128 g broadcast -> u16 combo.
__global__ __launch_bounds__(256) void k_phase1(const float* __restrict__ gt,
                                                const float* __restrict__ pr,
                                                uint16_t* __restrict__ combo,
                                                u64* __restrict__ rowpk2) {
  __shared__ __align__(16) float sp[TILE * 8];  // 4000 B
  __shared__ __align__(16) float sg[Gn * 8];    // 4096 B
  int blk = blockIdx.x;
  int b = blk >> 6, s = blk & 63;
  int tid = threadIdx.x;
  const float kNaN = __uint_as_float(0x7FC00000u);

  if (tid < TILE) {
    const float* pb = pr + ((size_t)b * Pn + s * TILE + tid) * 5;
    float c0 = pb[0], c1 = pb[1], c2 = pb[2], c3 = pb[3], v = pb[4];
    float area = __fmul_rn(__fsub_rn(c3, c1), __fsub_rn(c2, c0));
    if (v == 0.0f) area = kNaN;
    sp[tid * 8 + 0] = c0; sp[tid * 8 + 1] = c1; sp[tid * 8 + 2] = c2;
    sp[tid * 8 + 3] = c3; sp[tid * 8 + 4] = area;
  } else if (tid >= 128) {
    int g = tid - 128;
    const float* gb = gt + ((size_t)b * Gn + g) * 5;
    float c0 = gb[0], c1 = gb[1], c2 = gb[2], c3 = gb[3], v = gb[4];
    float area = __fmul_rn(__fsub_rn(c3, c1), __fsub_rn(c2, c0));
    if (v == 0.0f) area = kNaN;
    sg[g * 8 + 0] = c0; sg[g * 8 + 1] = c1; sg[g * 8 + 2] = c2;
    sg[g * 8 + 3] = c3; sg[g * 8 + 4] = area;
  }
  __syncthreads();

  int wave = tid >> 6, lane = tid & 63;
  if (wave < 2) {
    int g = (wave << 6) | lane;
    float4 gb = *(const float4*)&sg[g * 8];
    float ga = sg[g * 8 + 4];
    float best = -2.0f; int bestp = -1;
    for (int p = 0; p < TILE; p++) {
      float4 pb = *(const float4*)&sp[p * 8];  // broadcast
      float pa = sp[p * 8 + 4];
      float v = iou_pk(gb, ga, pb, pa);
      if (v > best) { best = v; bestp = p; }  // ascending p => lowest p on tie
    }
    u64 key = 0;
    if (bestp >= 0)
      key = ((u64)__float_as_uint(best) << 32) | (unsigned)(~(s * TILE + bestp));
    rowpk2[((size_t)b * SLICES + s) * Gn + g] = key;
  } else {
    int t2 = tid - 128;
    if (t2 < TILE) {
      float4 pb = *(const float4*)&sp[t2 * 8];
      float pa = sp[t2 * 8 + 4];
      float best = -2.0f; int bestg = -1;
      for (int g = 0; g < Gn; g++) {
        float4 gb = *(const float4*)&sg[g * 8];  // broadcast
        float ga = sg[g * 8 + 4];
        float v = iou_pk(gb, ga, pb, pa);
        if (v > best) { best = v; bestg = g; }  // ascending g => lowest g on tie
      }
      int cls = 0, pa_out = 0;
      if (bestg >= 0) { cls = (best >= 0.5f) ? 2 : 1; pa_out = bestg; }
      combo[(size_t)b * Pn + s * TILE + t2] = (uint16_t)((cls << 8) | pa_out);
    }
  }
}

// Per-batch: reduce rowpk2 -> removed bitmap, PRNG+classify+histogram,
// threshold scan, candidate gather, 512-wide bitonic sort, epilogue.
__global__ __launch_bounds__(1024) void k_select(
    const float* __restrict__ gt, const int* __restrict__ gtc,
    const float* __restrict__ pr, const uint16_t* __restrict__ combo,
    const u64* __restrict__ rowpk2, float* __restrict__ out) {
  __shared__ uint32_t skey[Pn];           // 32 KB: (cls<<23)|val23
  __shared__ uint32_t hist2[1024];
  __shared__ uint32_t hist1[1024];
  __shared__ u64 cand[CANDN];             // 4 KB
  __shared__ u64 pm8[1024];               // 8 KB rowpk partials
  __shared__ uint32_t rembm[Pn / 32 + 1];
  __shared__ int matched[Gn];
  __shared__ int s_npos, s_nneg, s_miss, s_call, s_cpos, s_T2, s_T1;
  __shared__ uint32_t s_keys[4];
  int b = blockIdx.x, tid = threadIdx.x;

  // rowpk2 reduction: thread (g = tid>>3, c = tid&7) covers 8 slices
  {
    int g = tid >> 3, c = tid & 7;
    const u64* base = rowpk2 + (size_t)b * SLICES * Gn + g;
    u64 m = 0;
#pragma unroll
    for (int i = 0; i < 8; i++) {
      u64 v = base[(size_t)(c * 8 + i) * Gn];
      if (v > m) m = v;
    }
    pm8[tid] = m;
  }
  hist2[tid] = 0; hist1[tid] = 0;
  if (tid < CANDN) cand[tid] = 0ull;
  if (tid < Pn / 32 + 1) rembm[tid] = 0;
  if (tid < Gn) matched[tid] = 0;
  if (tid == 0) {
    s_npos = 0; s_nneg = 0; s_miss = 0; s_call = 0; s_cpos = 0;
    s_T2 = 1025; s_T1 = 1025;
    // partitionable threefry: keys=split((0,42),16)[b]=tf(...,0,b); k1,k2=split
    uint32_t kb0, kb1, a0, a1, c0, c1;
    tf2x32(0u, 42u, 0u, (uint32_t)b, kb0, kb1);
    tf2x32(kb0, kb1, 0u, 0u, a0, a1);
    tf2x32(kb0, kb1, 0u, 1u, c0, c1);
    s_keys[0] = a0; s_keys[1] = a1; s_keys[2] = c0; s_keys[3] = c1;
  }
  __syncthreads();

  if (tid < Gn) {
    u64 m = 0;
#pragma unroll
    for (int i = 0; i < 8; i++) {
      u64 v = pm8[tid * 8 + i];
      if (v > m) m = v;
    }
    if (m != 0ull) {
      unsigned p = ~(unsigned)(m & 0xFFFFFFFFull);
      atomicOr(&rembm[p >> 5], 1u << (p & 31));
    }
  }
  __syncthreads();

  uint32_t k10 = s_keys[0], k11 = s_keys[1], k20 = s_keys[2], k21 = s_keys[3];
  const size_t bp = (size_t)b * Pn;
  int lpos = 0, lneg = 0;
  for (int p = tid; p < Pn; p += 1024) {
    uint32_t cb = combo[bp + p];
    int rem = (rembm[p >> 5] >> (p & 31)) & 1;
    int cls = rem ? 0 : (int)(cb >> 8);
    uint32_t key = 0;
    if (cls) {
      uint32_t kk0 = (cls == 2) ? k10 : k20, kk1 = (cls == 2) ? k11 : k21;
      uint32_t y0, y1;
      tf2x32(kk0, kk1, 0u, (uint32_t)p, y0, y1);
      uint32_t val = (y0 ^ y1) >> 9;
      key = ((uint32_t)cls << 23) | val;
      if (cls == 2) { lpos++; matched[cb & 127] = 1; atomicAdd(&hist2[val >> 13], 1u); }
      else { lneg++; atomicAdd(&hist1[val >> 13], 1u); }
    }
    skey[p] = key;
  }
  if (lpos) atomicAdd(&s_npos, lpos);
  if (lneg) atomicAdd(&s_nneg, lneg);
  __syncthreads();

  // threshold scan: wave0 -> positives, wave1 -> negatives
  if (tid < 128) {
    bool isP = tid < 64;
    int lane = tid & 63;
    uint32_t* hist = isP ? hist2 : hist1;
    int cnt = isP ? s_npos : s_nneg;
    int cap = isP ? POSCAP : Rn;
    int need = cnt < cap ? cnt : cap;
    int base = 1024 - 16 * (lane + 1);
    int local = 0;
#pragma unroll
    for (int j = 0; j < 16; j++) local += (int)hist[base + j];
    int incl = local;
    for (int d = 1; d < 64; d <<= 1) {
      int o = __shfl_up(incl, d);
      if (lane >= d) incl += o;
    }
    int above = incl - local;  // strictly-above-range count
    if (need > 0 && above < need && above + local >= need) {
      int cum = above, T = base;
      for (int j = 15; j >= 0; j--) {
        cum += (int)hist[base + j];
        if (cum >= need) { T = base + j; break; }
      }
      if (isP) s_T2 = T; else s_T1 = T;
    }
  }
  __syncthreads();
  int T2 = s_T2, T1 = s_T1;

  for (int p = tid; p < Pn; p += 1024) {
    uint32_t key = skey[p];
    int cls = (int)(key >> 23);
    if (cls) {
      int bucket = (int)((key & 0x7FFFFFu) >> 13);
      int T = (cls == 2) ? T2 : T1;
      if (bucket >= T) {
        int slot = atomicAdd(&s_call, 1);
        if (slot < CANDN) {
          cand[slot] = ((u64)key << 16) | (uint32_t)((uint16_t)(~p));
          if (cls == 2) atomicAdd(&s_cpos, 1);
        }
      }
    }
  }
  __syncthreads();

  // bitonic sort desc on u64 (strict total order: cls, val desc, idx asc)
  for (unsigned k = 2; k <= CANDN; k <<= 1) {
    for (unsigned j = k >> 1; j > 0; j >>= 1) {
      unsigned i = tid, l = i ^ j;
      if (i < CANDN && l > i) {
        u64 av = cand[i], cv = cand[l];
        bool a_first = av > cv;
        bool desc = ((i & k) == 0u);
        if (desc != a_first) { cand[i] = cv; cand[l] = av; }
      }
      __syncthreads();
    }
  }

  int npos = s_npos, nneg = s_nneg, cpos = s_cpos;
  int n_pos = npos < POSCAP ? npos : POSCAP;
  int rems = Rn - n_pos;
  int n_neg = nneg < rems ? nneg : rems;

  float* o_del = out;
  float* o_cls = out + (size_t)Bn * Rn * 5;
  float* o_roi = out + (size_t)Bn * Rn * 7;
  float* o_mis = out + (size_t)Bn * Rn * 12;

  if (tid < Rn) {
    int s = tid;
    bool is_pos = s < n_pos;
    bool is_real = s < n_pos + n_neg;
    float d0 = 0, d1 = 0, d2 = 0, d3 = 0, d4 = 0, c0 = 0, c1 = 0;
    float r0 = 0, r1 = 0, r2 = 0, r3 = 0, r4 = 0;
    if (is_real) {
      int ci = is_pos ? s : (cpos + (s - n_pos));
      u64 ck = cand[ci];
      int p = (int)((~(unsigned)ck) & 0xFFFFu);
      const float* pb = pr + (bp + p) * 5;
      float q0 = pb[0], q1 = pb[1], q2 = pb[2], q3 = pb[3];
      r0 = q0; r1 = q1; r2 = q2; r3 = q3; r4 = 1.0f; c1 = 1.0f;
      if (is_pos) {
        int g = (int)(combo[bp + p] & 127);
        const float* gb = gt + ((size_t)b * Gn + g) * 5;
        float g0 = gb[0], g1 = gb[1], g2 = gb[2], g3 = gb[3];
        float h = __fsub_rn(q2, q0), w = __fsub_rn(q3, q1);
        float gh = __fsub_rn(g2, g0), gw = __fsub_rn(g3, g1);
        float cy = __fmul_rn(__fadd_rn(q2, q0), 0.5f);
        float cx = __fmul_rn(__fadd_rn(q3, q1), 0.5f);
        float gcy = __fmul_rn(__fadd_rn(g2, g0), 0.5f);
        float gcx = __fmul_rn(__fadd_rn(g3, g1), 0.5f);
        float dy = __fdiv_rn(__fsub_rn(gcy, cy), h);
        float dx = __fdiv_rn(__fsub_rn(gcx, cx), w);
        float dh = logf(fmaxf(__fdiv_rn(gh, h), 1e-8f));
        float dw = logf(fmaxf(__fdiv_rn(gw, w), 1e-8f));
        d0 = __fdiv_rn(dy, 0.1f); d1 = __fdiv_rn(dx, 0.1f);
        d2 = __fdiv_rn(dh, 0.2f); d3 = __fdiv_rn(dw, 0.2f);
        d4 = 1.0f;
        c0 = (float)gtc[((size_t)b * Gn + g) * 2];
      } else {
        d4 = -1.0f;
      }
    }
    size_t ob = (size_t)b * Rn + s;
    o_del[ob * 5 + 0] = d0; o_del[ob * 5 + 1] = d1; o_del[ob * 5 + 2] = d2;
    o_del[ob * 5 + 3] = d3; o_del[ob * 5 + 4] = d4;
    o_cls[ob * 2 + 0] = c0; o_cls[ob * 2 + 1] = c1;
    o_roi[ob * 5 + 0] = r0; o_roi[ob * 5 + 1] = r1; o_roi[ob * 5 + 2] = r2;
    o_roi[ob * 5 + 3] = r3; o_roi[ob * 5 + 4] = r4;
  }

  if (tid < Gn) {
    float gv = gt[((size_t)b * Gn + tid) * 5 + 4];
    if (gv != 0.0f && matched[tid] == 0) atomicAdd(&s_miss, 1);
  }
  __syncthreads();
  if (tid == 0) o_mis[b] = (float)s_miss;
}

extern "C" void kernel_launch(void* const* d_in, const int* in_sizes, int n_in,
                              void* d_out, int out_size, void* d_ws, size_t ws_size,
                              hipStream_t stream) {
  const float* gt = (const float*)d_in[0];
  const int* gtc = (const int*)d_in[1];
  const float* pr = (const float*)d_in[2];
  float* out = (float*)d_out;

  u64* rowpk2 = (u64*)d_ws;                                  // B*SLICES*G u64 = 1 MB
  uint16_t* combo = (uint16_t*)(rowpk2 + Bn * SLICES * Gn);  // B*P u16 = 256 KB

  k_phase1<<<Bn * SLICES, 256, 0, stream>>>(gt, pr, combo, rowpk2);
  k_select<<<Bn, 1024, 0, stream>>>(gt, gtc, pr, combo, rowpk2, out);
}